// Round 1
// 1338.337 us; speedup vs baseline: 1.1289x; 1.1289x over previous
//
#include <hip/hip_runtime.h>

// One wave owns 16 vehicles for all 1000 steps. No __syncthreads anywhere.
// z-MFMA operand swap: A = W^T (rows = interleaved z-cols), B = [cur|h]^T.
// Unit->lane map: MFMA p gives lane (col,q) the 4 gate pre-activations of
// unit u = 4q+p (p<4) / 16+q (p=4), so the h writeback is one ds_write_b64
// (+1 b16) and ALL h consumers (phase-C hfrag + next-step z bfrag) are
// served by 3 uniform ds_read_b64 at per-lane precomputed addresses.
// pos/spd live replicated in registers of all 4 q-lanes of a vehicle
// (phase D = in-register dots + shfl_xor reduce) -> no pos_lds / x_lds.
// Block = 128 (2 independent waves), grid = 256 => 1 block/CU.

typedef __attribute__((ext_vector_type(8))) short short8;
typedef __attribute__((ext_vector_type(4))) short short4v;
typedef __attribute__((ext_vector_type(4))) float float4v;
typedef __attribute__((ext_vector_type(2))) float float2v;

__device__ __forceinline__ short f2b(float f) {
    unsigned u = __float_as_uint(f);
    u += 0x7fffu + ((u >> 16) & 1u);
    return (short)(u >> 16);
}

__device__ __forceinline__ float fast_exp2(float x) {
#if __has_builtin(__builtin_amdgcn_exp2f)
    return __builtin_amdgcn_exp2f(x);
#else
    return exp2f(x);
#endif
}
__device__ __forceinline__ float fast_rcp(float x) {
#if __has_builtin(__builtin_amdgcn_rcpf)
    return __builtin_amdgcn_rcpf(x);
#else
    return 1.0f / x;
#endif
}

#define L2E 1.44269504088896340736f

__global__ void __launch_bounds__(128) rnncf_kernel(
    const float* __restrict__ inp,        // (8192,1000,12)
    const float* __restrict__ init_state, // (8192,2)
    const float* __restrict__ h0g,        // (8192,20)
    const float* __restrict__ c0g,        // (8192,20)
    const float* __restrict__ Wk,         // (12,80)
    const float* __restrict__ Wr,         // (20,80)
    const float* __restrict__ bz_g,       // (80,)
    const float* __restrict__ W2,         // (20,10)
    const float* __restrict__ b2_g,       // (10,)
    const float* __restrict__ Wlc,        // (10,3)
    const float* __restrict__ blc,        // (3,)
    const float* __restrict__ Wd1,        // (10,1)
    const float* __restrict__ bd1,        // (1,)
    float* __restrict__ out)
{
    // per-wave LDS: h only. rows padded to 36 shorts (72 B).
    __shared__ short h_lds[2][16 * 36];

    const int tid = threadIdx.x;
    const int wv  = tid >> 6;
    const int l   = tid & 63;
    const int q   = l >> 4;      // quad 0..3
    const int col = l & 15;      // vehicle within wave
    const int v0  = (blockIdx.x * 2 + wv) * 16;

    short* hl  = h_lds[wv];
    char*  hl8 = (char*)hl;

    float* out_pos = out;                 // 8192*1000
    float* out_lc  = out + 8192000;       // 8192*1000*3
    float* out_spd = out + 32768000;      // 8192
    float* out_h   = out + 32776192;      // 8192*20
    float* out_c   = out + 32940032;      // 8192*20

    // ---- z-phase weight prep ----
    const int g  = col & 3;              // gate of this lane's A-row
    const int cu = col >> 2;
    const float sg_a = (g == 2) ? 2.0f * L2E : -L2E;

    short8  w1t[5];
    float4v bz1[5];
#pragma unroll
    for (int p = 0; p < 5; ++p) {
        const int ua = (p < 4) ? (4 * cu + p) : (16 + cu);  // unit of A-row
        const int n  = g * 20 + ua;                          // original z column
#pragma unroll
        for (int j = 0; j < 8; ++j) {
            int k = 8 * q + j;
            float wvl = (k < 12) ? Wk[k * 80 + n] : Wr[(k - 12) * 80 + n];
            w1t[p][j] = f2b(wvl * sg_a);
        }
        const int ud = (p < 4) ? (4 * q + p) : (16 + q);    // unit this lane owns
#pragma unroll
        for (int r = 0; r < 4; ++r) {
            float sr = (r == 2) ? 2.0f * L2E : -L2E;
            bz1[p][r] = sr * bz_g[r * 20 + ud];
        }
    }

    // ---- phase-C prep: A[n=col][k=u] = W2[u][n] ----
    short8 w2t;
#pragma unroll
    for (int j = 0; j < 8; ++j) {
        int k = 8 * q + j;
        float v = (col < 10 && k < 20) ? W2[k * 10 + col] : 0.0f;
        w2t[j] = f2b(v);
    }
    float4v bx;
#pragma unroll
    for (int r = 0; r < 4; ++r) { int n = 4 * q + r; bx[r] = (n < 10) ? b2_g[n] : 0.0f; }

    // ---- phase-D prep: lane (col,q) holds x feats f=4q+r; 4 outputs o ----
    float wd3[4][4];
#pragma unroll
    for (int r = 0; r < 4; ++r) {
        int f = 4 * q + r;
#pragma unroll
        for (int o = 0; o < 4; ++o)
            wd3[r][o] = (f < 10) ? ((o < 3) ? Wlc[f * 3 + o] : Wd1[f]) : 0.0f;
    }
    const float lc_bias = (q < 3) ? blc[q] : 0.0f;
    const float bd1v    = bd1[0];

    // ---- per-lane LDS byte addresses (3 uniform b64 reads per step) ----
    // r1: hfrag lo  (q0:u0-3  q1:u8-11  q2:u16-19 q3:dc)
    // r2: hfrag hi / bfrag (q0:u4-7 q1:u12-15 q2:u4-7 q3:u16-19)
    // r3: bfrag (q1:u0-3 q2:u8-11)
    const int base = col * 72;
    const int o1 = (q == 0) ? 0 : (q == 1) ? 16 : (q == 2) ? 32 : 24;
    const int o2 = (q == 0) ? 8 : (q == 1) ? 24 : (q == 2) ? 8  : 32;
    const int o3 = (q == 2) ? 16 : 0;
    const int a1 = base + o1, a2 = base + o2, a3 = base + o3;
    const int awr = base + 8 * q;   // b64 h write: units 4q..4q+3

    // ---- state init ----
    float c_st[5], h_keep[5];
#pragma unroll
    for (int p = 0; p < 5; ++p) {
        const int ud = (p < 4) ? (4 * q + p) : (16 + q);
        c_st[p] = c0g[(size_t)(v0 + col) * 20 + ud];
        h_keep[p] = 0.0f;
    }
    for (int i = l; i < 16 * 36; i += 64) hl[i] = 0;   // zero incl. pad u=20..35
    {
        short4v h0w;
#pragma unroll
        for (int p = 0; p < 4; ++p)
            h0w[p] = f2b(h0g[(size_t)(v0 + col) * 20 + 4 * q + p]);
        *(short4v*)(hl8 + awr) = h0w;
        hl[col * 36 + 16 + q] = f2b(h0g[(size_t)(v0 + col) * 20 + 16 + q]);
    }

    float2v ps = *(const float2v*)(init_state + (size_t)(v0 + col) * 2);
    float pos = ps[0], spd = ps[1];

    // ---- input prefetch (t = 0) ----
    const float* ipbase = inp + (size_t)(v0 + col) * 12000;
    float4v inA = {0, 0, 0, 0}, inB = {0, 0, 0, 0}, inC = {0, 0, 0, 0};
    if (q == 0)      { inA = *(const float4v*)(ipbase); inB = *(const float4v*)(ipbase + 4); }
    else if (q == 1) { inC = *(const float4v*)(ipbase + 8); }

    // prologue h reads (DS is in-order per wave: sees the init writes)
    short4v r1 = *(const short4v*)(hl8 + a1);
    short4v r2 = *(const short4v*)(hl8 + a2);
    short4v r3 = *(const short4v*)(hl8 + a3);

#pragma unroll 2
    for (int t = 0; t < 1000; ++t) {
        // ---- build B-frag for step t: B[k=8q+j][m=col] = [cur(12) | h(20)] ----
        short8 bfrag;
        if (q == 0) {
            float pp = pos * 0.01f;
            bfrag[0] = f2b(__builtin_fmaf(inA[0],  0.01f, -pp));
            bfrag[1] = f2b(__builtin_fmaf(inA[1],  0.01f, -pp));
            bfrag[2] = f2b(__builtin_fmaf(inA[2],  0.01f, -pp));
            bfrag[3] = f2b(__builtin_fmaf(inA[3], -0.01f,  pp));
            bfrag[4] = f2b(__builtin_fmaf(inB[0], -0.01f,  pp));
            bfrag[5] = f2b(__builtin_fmaf(inB[1], -0.01f,  pp));
            bfrag[6] = f2b(inB[2] * 0.025f);
            bfrag[7] = f2b(inB[3] * 0.025f);
        } else if (q == 1) {
            bfrag[0] = f2b(inC[0] * 0.025f);
            bfrag[1] = f2b(inC[1] * 0.025f);
            bfrag[2] = f2b(inC[2] * 0.025f);
            bfrag[3] = f2b(inC[3] * 0.025f);
            bfrag[4] = r3[0]; bfrag[5] = r3[1]; bfrag[6] = r3[2]; bfrag[7] = r3[3];
        } else if (q == 2) {
            bfrag[0] = r2[0]; bfrag[1] = r2[1]; bfrag[2] = r2[2]; bfrag[3] = r2[3];
            bfrag[4] = r3[0]; bfrag[5] = r3[1]; bfrag[6] = r3[2]; bfrag[7] = r3[3];
        } else {
            bfrag[0] = r1[0]; bfrag[1] = r1[1]; bfrag[2] = r1[2]; bfrag[3] = r1[3];
            bfrag[4] = r2[0]; bfrag[5] = r2[1]; bfrag[6] = r2[2]; bfrag[7] = r2[3];
        }

        // ---- z = W1sc^T @ [cur|h]^T : lane gets i,f,g,o of unit u(q,p) ----
        float4v z[5];
#pragma unroll
        for (int p = 0; p < 5; ++p)
            z[p] = __builtin_amdgcn_mfma_f32_16x16x32_bf16(w1t[p], bfrag, bz1[p], 0, 0, 0);

        // ---- prefetch inputs for t+1 (overlaps with gates) ----
        {
            int tn = (t < 999) ? t + 1 : 999;
            const float* ipn = ipbase + tn * 12;
            if (q == 0)      { inA = *(const float4v*)(ipn); inB = *(const float4v*)(ipn + 4); }
            else if (q == 1) { inC = *(const float4v*)(ipn + 8); }
        }

        // ---- gates (z pre-scaled: exp2 direct; exp2 underflow is benign,
        //      only upper clamps needed) ----
        short4v hw;
        short h16 = 0;
#pragma unroll
        for (int p = 0; p < 5; ++p) {
            float zi = fminf(z[p][0], 29.f);
            float zf = fminf(z[p][1], 29.f);
            float zg = fminf(z[p][2], 58.f);
            float zo = fminf(z[p][3], 29.f);
            float eA = fast_exp2(zi);   // e^{-z_i}
            float eB = fast_exp2(zf);   // e^{-z_f}
            float eC = fast_exp2(zg);   // e^{2 z_g}
            float eD = fast_exp2(zo);   // e^{-z_o}
            float pA = 1.0f + eA, pB = 1.0f + eB, pC = eC + 1.0f, mC = eC - 1.0f;
            float t1 = pA * pC;
            float R  = fast_rcp(t1 * pB);
            float cn = (c_st[p] * t1 + mC * pB) * R;   // sig(f)c + sig(i)tanh(g)
            c_st[p] = cn;
            float ec = fminf(cn * (2.0f * L2E), 58.f);
            float eE = fast_exp2(ec);
            float h  = (eE - 1.0f) * fast_rcp((1.0f + eD) * (eE + 1.0f));
            h_keep[p] = h;
            short hb = f2b(h);
            if (p < 4) hw[p] = hb; else h16 = hb;
        }
        *(short4v*)(hl8 + awr) = hw;        // units 4q..4q+3
        hl[col * 36 + 16 + q] = h16;        // unit 16+q

        // ---- the 3 uniform b64 reads (serve phase-C hfrag AND next bfrag) ----
        r1 = *(const short4v*)(hl8 + a1);
        r2 = *(const short4v*)(hl8 + a2);
        r3 = *(const short4v*)(hl8 + a3);

        // ---- phase C: x = relu(W2^T @ h^T + b2). hfrag = {r1,r2} uniformly:
        //      slots where the data is "wrong" hit zero A-columns (finite*0=0).
        short8 hfrag;
        hfrag[0] = r1[0]; hfrag[1] = r1[1]; hfrag[2] = r1[2]; hfrag[3] = r1[3];
        hfrag[4] = r2[0]; hfrag[5] = r2[1]; hfrag[6] = r2[2]; hfrag[7] = r2[3];
        float4v x4 = __builtin_amdgcn_mfma_f32_16x16x32_bf16(w2t, hfrag, bx, 0, 0, 0);
        float xr[4];
#pragma unroll
        for (int r = 0; r < 4; ++r) xr[r] = fmaxf(x4[r], 0.0f);

        // ---- phase D: per-lane partial dots over own 4 feats, shfl-reduce
        //      over the 4 q-lanes -> every lane holds all 4 outputs ----
        float pd[4];
#pragma unroll
        for (int o = 0; o < 4; ++o) {
            float s = xr[0] * wd3[0][o];
            s = __builtin_fmaf(xr[1], wd3[1][o], s);
            s = __builtin_fmaf(xr[2], wd3[2][o], s);
            s = __builtin_fmaf(xr[3], wd3[3][o], s);
            s += __shfl_xor(s, 16);
            s += __shfl_xor(s, 32);
            pd[o] = s;
        }
        float lcv = pd[0];
        lcv = (q == 1) ? pd[1] : lcv;
        lcv = (q == 2) ? pd[2] : lcv;
        if (q < 3)
            out_lc[(size_t)(v0 + col) * 3000 + t * 3 + q] = lcv + lc_bias;

        // pos_{t+1} = pos_t + DT*spd_t (entry spd), then spd update
        pos = __builtin_fmaf(0.1f, spd, pos);
        if (q == 0) out_pos[(size_t)(v0 + col) * 1000 + t] = pos;
        float acc = __builtin_fmaf(10.0f, pd[3] + bd1v, -6.0f);
        spd = __builtin_fmaf(0.1f, acc, spd);
    }

    // ---- finals ----
    if (q == 0) out_spd[v0 + col] = spd;
#pragma unroll
    for (int p = 0; p < 5; ++p) {
        const int ud = (p < 4) ? (4 * q + p) : (16 + q);
        out_h[(size_t)(v0 + col) * 20 + ud] = h_keep[p];
        out_c[(size_t)(v0 + col) * 20 + ud] = c_st[p];
    }
}

extern "C" void kernel_launch(void* const* d_in, const int* in_sizes, int n_in,
                              void* d_out, int out_size, void* d_ws, size_t ws_size,
                              hipStream_t stream) {
    rnncf_kernel<<<256, 128, 0, stream>>>(
        (const float*)d_in[0],  (const float*)d_in[1],  (const float*)d_in[2],
        (const float*)d_in[3],  (const float*)d_in[4],  (const float*)d_in[5],
        (const float*)d_in[6],  (const float*)d_in[7],  (const float*)d_in[8],
        (const float*)d_in[9],  (const float*)d_in[10], (const float*)d_in[11],
        (const float*)d_in[12], (float*)d_out);
}